// Round 4
// baseline (4620.993 us; speedup 1.0000x reference)
//
#include <hip/hip_runtime.h>
#include <cstddef>

typedef unsigned int  uint;
typedef unsigned short ushort_t;
typedef __attribute__((ext_vector_type(8))) short bf16x8;     // 8 bf16 (4 VGPRs) - MFMA A/B frag
typedef __attribute__((ext_vector_type(8))) _Float16 f16x8;   // 8 f16  (4 VGPRs) - MFMA A/B frag
typedef __attribute__((ext_vector_type(4))) float f32x4;      // MFMA C/D frag
typedef __attribute__((ext_vector_type(2))) _Float16 h2_t;

// ---------- scalar conversion helpers ----------
__device__ __forceinline__ short f2bs(float x) {            // f32 -> bf16 bits (RNE)
    union { float f; uint u; } v; v.f = x;
    uint r = v.u + 0x7FFF + ((v.u >> 16) & 1);
    return (short)(r >> 16);
}
__device__ __forceinline__ ushort_t f16b(float x) {         // f32 -> f16 bits
    _Float16 h = (_Float16)x; return __builtin_bit_cast(ushort_t, h);
}
__device__ __forceinline__ float h2f(ushort_t u) {
    return (float)__builtin_bit_cast(_Float16, u);
}
__device__ __forceinline__ float fast_sigmoid(float x) {
    float e = __builtin_amdgcn_exp2f(-1.4426950408889634f * x);
    return __builtin_amdgcn_rcpf(1.f + e);
}
__device__ __forceinline__ float fast_tanh(float x) {
    float e = __builtin_amdgcn_exp2f(2.8853900817779268f * x);
    return 1.f - 2.f * __builtin_amdgcn_rcpf(e + 1.f);
}

#define MFMA16(a,b,c) __builtin_amdgcn_mfma_f32_16x16x32_bf16((a),(b),(c),0,0,0)
#define MFMAH(a,b,c)  __builtin_amdgcn_mfma_f32_16x16x32_f16((a),(b),(c),0,0,0)

// ======================= prep kernels =======================
// x f32 [64][1024][256] -> bf16
__global__ void k_prep_x(const float* __restrict__ x, short* __restrict__ xb) {
    int i = (blockIdx.x * 256 + threadIdx.x) * 4;
    float4 v = *(const float4*)&x[i];
    short o[4] = { f2bs(v.x), f2bs(v.y), f2bs(v.z), f2bs(v.w) };
    *(uint2*)&xb[i] = *(uint2*)o;
}
// WkT[n][k] bf16, n in [0,1536): fwd cols then bwd cols
__global__ void k_prep_wk(const float* __restrict__ kf, const float* __restrict__ kb,
                          short* __restrict__ wkt) {
    int n = blockIdx.x, k = threadIdx.x;
    float v = (n < 768) ? kf[k * 768 + n] : kb[k * 768 + (n - 768)];
    wkt[n * 256 + k] = f2bs(v);
}
// recurrent weights transposed f16: wrt[dir][n][k] = Wr_dir[k][n], n in [0,768), k in [0,256)
// (MFMA B^T-frag source, same structure as k_prep_wk which is proven)
__global__ void k_prep_wrt(const float* __restrict__ wrf, const float* __restrict__ wrb,
                           ushort_t* __restrict__ wrt) {
    int n = blockIdx.x, k = threadIdx.x;     // n in [0,1536): fwd then bwd
    float v = (n < 768) ? wrf[k * 768 + n] : wrb[k * 768 + (n - 768)];
    wrt[n * 256 + k] = f16b(v);
}
// WbT_perm[kappa][e] bf16 ; kappa = k*256+n2 ; f = n2*7+k
__global__ void k_prep_wb(const float* __restrict__ wb, short* __restrict__ wbt) {
    int kp = blockIdx.x, e = threadIdx.x;
    int n2 = kp & 255, kk = kp >> 8;
    int f = n2 * 7 + kk;
    wbt[kp * 256 + e] = f2bs(wb[e * 1792 + f]);
}

// ======================= projection GEMM =======================
// [65536 x 256] @ [256 x 1536] -> xp f16 [dir][b][t][768] (+b[0], bwd time-reversed)
__global__ __launch_bounds__(512) void k_proj(const short* __restrict__ xb,
        const short* __restrict__ wkt, const float* __restrict__ gbf,
        const float* __restrict__ gbb, ushort_t* __restrict__ xp) {
    __shared__ union {
        struct { short A[128 * 40]; short B[128 * 40]; } st;
        ushort_t E[128 * 136];
    } u;
    int bid = blockIdx.x;
    int nt = bid % 12, mt = bid / 12;
    int r0 = mt * 128, n0 = nt * 128;
    int tid = threadIdx.x, lane = tid & 63, wid = tid >> 6;
    int wm = wid & 1, wn = wid >> 1;
    int q = lane >> 4, c = lane & 15;
    f32x4 acc[4][2];
#pragma unroll
    for (int mi = 0; mi < 4; mi++)
#pragma unroll
        for (int ni = 0; ni < 2; ni++) acc[mi][ni] = (f32x4){0.f, 0.f, 0.f, 0.f};
    int si = tid >> 2, sp = tid & 3;
    for (int kt = 0; kt < 8; kt++) {
        int k0 = kt * 32;
        *(uint4*)&u.st.A[si * 40 + sp * 8] = *(const uint4*)&xb[(r0 + si) * 256 + k0 + sp * 8];
        *(uint4*)&u.st.B[si * 40 + sp * 8] = *(const uint4*)&wkt[(n0 + si) * 256 + k0 + sp * 8];
        __syncthreads();
        bf16x8 af[4], bfr[2];
#pragma unroll
        for (int mi = 0; mi < 4; mi++) af[mi] = *(bf16x8*)&u.st.A[(wm * 64 + mi * 16 + c) * 40 + q * 8];
#pragma unroll
        for (int ni = 0; ni < 2; ni++) bfr[ni] = *(bf16x8*)&u.st.B[(wn * 32 + ni * 16 + c) * 40 + q * 8];
#pragma unroll
        for (int mi = 0; mi < 4; mi++)
#pragma unroll
            for (int ni = 0; ni < 2; ni++) acc[mi][ni] = MFMA16(af[mi], bfr[ni], acc[mi][ni]);
        __syncthreads();
    }
#pragma unroll
    for (int ni = 0; ni < 2; ni++) {
        int ng = n0 + wn * 32 + ni * 16 + c;
        bool d1 = ng >= 768; int nb = d1 ? ng - 768 : ng;
        float bias = d1 ? gbb[nb] : gbf[nb];
#pragma unroll
        for (int mi = 0; mi < 4; mi++)
#pragma unroll
            for (int v = 0; v < 4; v++) {
                int rl = wm * 64 + mi * 16 + q * 4 + v;
                u.E[rl * 136 + wn * 32 + ni * 16 + c] = f16b(acc[mi][ni][v] + bias);
            }
    }
    __syncthreads();
    {
        int i = tid >> 2, p = tid & 3;
        int r = r0 + i, b = r >> 10, t = r & 1023;
        int ng = n0 + p * 32;
        const ushort_t* src = &u.E[i * 136 + p * 32];
        ushort_t* dst;
        if (ng < 768) dst = xp + (size_t)(b * 1024 + t) * 768 + ng;
        else          dst = xp + 50331648ull + (size_t)(b * 1024 + (1023 - t)) * 768 + (ng - 768);
#pragma unroll
        for (int v = 0; v < 4; v++) *(uint4*)&dst[v * 8] = *(const uint4*)&src[v * 8];
    }
}

// ======================= GRU recurrence (MFMA-batched) =======================
// 8 WGs x 512 thr: WG g owns 16 streams (dir = g>>2, b = (g&3)*16 + m).
// Per step: a[16 streams][768 cols] = h[16][256] @ Wr[256][768] via
// mfma_f32_16x16x32_f16 (f16 in / f32 acc, same numerics class as prior fdot2).
// Wave w owns cols {gate*256 + w*32 .. +32} for all 3 gates = 6 ntiles;
// B^T frags (48 x f16x8 = 192 regs -> AGPRs) loaded once from wrt[n][k].
// h lives in LDS [m][j] f16 with XOR swizzle (byte ^= (m&7)<<4) on BOTH
// write and read. Conflict audit: b128 service granularity is 8 lanes x 16B
// = one 128B bank row; within each 8-lane group phys slots = (kt*4+q)^(c&7)
// mod 8 -> permutation of 0..7 -> conflict-free.
// Zero cross-lane shuffles (r2 post-mortem: wave64 shuffles ~30cyc on the
// per-CU LDS pipe dominated the step); MFMA does the K-reduction.
// x-projections: 24 scalar u16 loads/lane issued at step top, consumed after
// the MFMA block (~1000 cyc later) -> HBM latency hidden in-step.
__global__ __launch_bounds__(512, 2) void k_gru(const ushort_t* __restrict__ wrt,
        const ushort_t* __restrict__ xp, const float* __restrict__ gbf,
        const float* __restrict__ gbb, float* __restrict__ cbuf) {
    int g = blockIdx.x;                 // 8 WGs, 16 streams each
    int dir = g >> 2;
    int tid = threadIdx.x;
    int lane = tid & 63, w = tid >> 6;  // wave w: cols w*32..w*32+32 within each gate
    int c = lane & 15, q = lane >> 4;   // c: B^T-row/A-row select; q: k-subgroup, C-row-group
    int bq = (g & 3) * 16 + q * 4;      // first of this lane's 4 C-row streams

    // ---- B^T frags: wfr[gate*2+sub][kt]: lane holds
    //      Wr^T[n = gate*256 + w*32 + sub*16 + c][k = kt*32 + q*8 .. +7]
    const ushort_t* WD = wrt + (size_t)dir * 196608;
    f16x8 wfr[6][8];
#pragma unroll
    for (int nt = 0; nt < 6; nt++) {
        int gate = nt >> 1, sub = nt & 1;
        const ushort_t* wp = WD + (size_t)(gate * 256 + w * 32 + sub * 16 + c) * 256 + q * 8;
#pragma unroll
        for (int kt = 0; kt < 8; kt++)
            wfr[nt][kt] = *(const f16x8*)(wp + kt * 32);
    }

    // ---- biases b[1] per col
    const float* bsr = (dir ? gbb : gbf) + 768;
    float bz[2], br[2], bn[2];
#pragma unroll
    for (int sub = 0; sub < 2; sub++) {
        int j = w * 32 + sub * 16 + c;
        bz[sub] = bsr[j]; br[sub] = bsr[256 + j]; bn[sub] = bsr[512 + j];
    }

    // ---- x pointers: 4 streams (this lane's C rows), base col = w*32 + c
    const ushort_t* X0 = xp + (size_t)(dir * 64 + bq + 0) * 786432 + w * 32 + c;
    const ushort_t* X1 = xp + (size_t)(dir * 64 + bq + 1) * 786432 + w * 32 + c;
    const ushort_t* X2 = xp + (size_t)(dir * 64 + bq + 2) * 786432 + w * 32 + c;
    const ushort_t* X3 = xp + (size_t)(dir * 64 + bq + 3) * 786432 + w * 32 + c;

    __shared__ ushort_t hbuf[2][16 * 256];   // [buf][m][j] f16, XOR-swizzled, 2x8KB
    {
        uint4* p = (uint4*)&hbuf[0][0];
        p[tid] = (uint4){0u, 0u, 0u, 0u};    // 512*16B = 8KB: zero h(0)
    }
    __syncthreads();

    float hreg[2][4];
#pragma unroll
    for (int sub = 0; sub < 2; sub++)
#pragma unroll
        for (int v = 0; v < 4; v++) hreg[sub][v] = 0.f;

    const int xorm = (lane & 7) << 4;        // A-read swizzle term ((m&7)<<4, m = lane&15)

#pragma unroll 1
    for (int tt = 0; tt < 1024; tt++) {
        // x loads for THIS step (consumed after MFMAs)
        ushort_t xv[3][2][4];
#pragma unroll
        for (int sub = 0; sub < 2; sub++) {
            int o = sub * 16;
            xv[0][sub][0] = X0[o]; xv[1][sub][0] = X0[256 + o]; xv[2][sub][0] = X0[512 + o];
            xv[0][sub][1] = X1[o]; xv[1][sub][1] = X1[256 + o]; xv[2][sub][1] = X1[512 + o];
            xv[0][sub][2] = X2[o]; xv[1][sub][2] = X2[256 + o]; xv[2][sub][2] = X2[512 + o];
            xv[0][sub][3] = X3[o]; xv[1][sub][3] = X3[256 + o]; xv[2][sub][3] = X3[512 + o];
        }
        X0 += 768; X1 += 768; X2 += 768; X3 += 768;

        // A-frags from h-LDS + 48 MFMA
        const char* hbp = (const char*)&hbuf[tt & 1][0] + (lane & 15) * 512;
        f32x4 acc[6];
#pragma unroll
        for (int nt = 0; nt < 6; nt++) acc[nt] = (f32x4){0.f, 0.f, 0.f, 0.f};
#pragma unroll
        for (int kt = 0; kt < 8; kt++) {
            f16x8 af = *(const f16x8*)(hbp + ((kt * 64 + q * 16) ^ xorm));
#pragma unroll
            for (int nt = 0; nt < 6; nt++) acc[nt] = MFMAH(af, wfr[nt][kt], acc[nt]);
        }

        // gates + h update + swizzled h write
        char* wb = (char*)&hbuf[(tt & 1) ^ 1][0];
#pragma unroll
        for (int sub = 0; sub < 2; sub++)
#pragma unroll
            for (int v = 0; v < 4; v++) {
                float z  = fast_sigmoid(h2f(xv[0][sub][v]) + acc[sub][v]     + bz[sub]);
                float r  = fast_sigmoid(h2f(xv[1][sub][v]) + acc[2 + sub][v] + br[sub]);
                float hh = fast_tanh   (h2f(xv[2][sub][v]) + r * (acc[4 + sub][v] + bn[sub]));
                float hn = z * hreg[sub][v] + (1.f - z) * hh;
                hreg[sub][v] = hn;
                int mw = q * 4 + v;
                int jb = (w * 32 + sub * 16 + c) * 2;
                *(ushort_t*)(wb + mw * 512 + (jb ^ ((mw & 7) << 4))) = f16b(hn);
            }
        __syncthreads();
    }

    // epilogue: c = [hf | hb]
#pragma unroll
    for (int sub = 0; sub < 2; sub++)
#pragma unroll
        for (int v = 0; v < 4; v++) {
            int b = bq + v;
            int j = w * 32 + sub * 16 + c;
            cbuf[b * 512 + dir * 256 + j] = hreg[sub][v];
        }
}

// ======================= hyper1: a = c @ Wa =======================
// [64 x 512] @ [512 x 65536] -> a bf16 [64][65536]
__global__ __launch_bounds__(256) void k_hyper1(const float* __restrict__ cbuf,
        const float* __restrict__ Wa, short* __restrict__ aout) {
    __shared__ union {
        struct { short A[64 * 40]; short B[128 * 40]; } st;
        ushort_t E[64 * 136];
    } u;
    int nt = blockIdx.x, n0 = nt * 128;
    int tid = threadIdx.x, lane = tid & 63, wid = tid >> 6;  // 4 waves, wave-tile 64x32
    int q = lane >> 4, c = lane & 15;
    f32x4 acc[4][2];
#pragma unroll
    for (int mi = 0; mi < 4; mi++)
#pragma unroll
        for (int ni = 0; ni < 2; ni++) acc[mi][ni] = (f32x4){0.f, 0.f, 0.f, 0.f};
    for (int kt = 0; kt < 16; kt++) {
        int k0 = kt * 32;
        {   // A 64x32 from cbuf f32 -> bf16
            int i = tid >> 2, p = tid & 3;
            const float* s = &cbuf[i * 512 + k0 + p * 8];
            short tmp[8];
#pragma unroll
            for (int v = 0; v < 8; v++) tmp[v] = f2bs(s[v]);
            *(uint4*)&u.st.A[i * 40 + p * 8] = *(uint4*)tmp;
        }
        {   // B: Wa[k][n] -> LDS [n][k] transposed
            int kk = tid >> 3, nn0 = (tid & 7) * 16;
            const float* s = &Wa[(size_t)(k0 + kk) * 65536 + n0 + nn0];
#pragma unroll
            for (int l = 0; l < 16; l++) u.st.B[(nn0 + l) * 40 + kk] = f2bs(s[l]);
        }
        __syncthreads();
        bf16x8 af[4], bfr[2];
#pragma unroll
        for (int mi = 0; mi < 4; mi++) af[mi] = *(bf16x8*)&u.st.A[(mi * 16 + c) * 40 + q * 8];
#pragma unroll
        for (int ni = 0; ni < 2; ni++) bfr[ni] = *(bf16x8*)&u.st.B[(wid * 32 + ni * 16 + c) * 40 + q * 8];
#pragma unroll
        for (int mi = 0; mi < 4; mi++)
#pragma unroll
            for (int ni = 0; ni < 2; ni++) acc[mi][ni] = MFMA16(af[mi], bfr[ni], acc[mi][ni]);
        __syncthreads();
    }
#pragma unroll
    for (int ni = 0; ni < 2; ni++)
#pragma unroll
        for (int mi = 0; mi < 4; mi++)
#pragma unroll
            for (int v = 0; v < 4; v++)
                u.E[(mi * 16 + q * 4 + v) * 136 + wid * 32 + ni * 16 + c] =
                    (ushort_t)f2bs(acc[mi][ni][v]);
    __syncthreads();
    {
        int i = tid >> 2, p = tid & 3;
        short* dst = aout + (size_t)i * 65536 + n0 + p * 32;
        const ushort_t* src = &u.E[i * 136 + p * 32];
#pragma unroll
        for (int v = 0; v < 4; v++) *(uint4*)&dst[v * 8] = *(const uint4*)&src[v * 8];
    }
}

// ======================= hyper2: fb = a @ WbT_perm =======================
// [16384 x 256] @ [256 x 1792] -> WconvT bf16 [b][co][kappa]
__global__ __launch_bounds__(512) void k_hyper2(const short* __restrict__ a,
        const short* __restrict__ wbt, short* __restrict__ wc) {
    __shared__ union {
        struct { short A[128 * 40]; short B[128 * 40]; } st;
        ushort_t E[128 * 136];
    } u;
    int bid = blockIdx.x;
    int nt = bid % 14, mt = bid / 14;
    int r0 = mt * 128, n0 = nt * 128;
    int tid = threadIdx.x, lane = tid & 63, wid = tid >> 6;
    int wm = wid & 1, wn = wid >> 1;
    int q = lane >> 4, c = lane & 15;
    f32x4 acc[4][2];
#pragma unroll
    for (int mi = 0; mi < 4; mi++)
#pragma unroll
        for (int ni = 0; ni < 2; ni++) acc[mi][ni] = (f32x4){0.f, 0.f, 0.f, 0.f};
    int si = tid >> 2, sp = tid & 3;
    for (int kt = 0; kt < 8; kt++) {
        int k0 = kt * 32;
        *(uint4*)&u.st.A[si * 40 + sp * 8] = *(const uint4*)&a[(r0 + si) * 256 + k0 + sp * 8];
        *(uint4*)&u.st.B[si * 40 + sp * 8] = *(const uint4*)&wbt[(n0 + si) * 256 + k0 + sp * 8];
        __syncthreads();
        bf16x8 af[4], bfr[2];
#pragma unroll
        for (int mi = 0; mi < 4; mi++) af[mi] = *(bf16x8*)&u.st.A[(wm * 64 + mi * 16 + c) * 40 + q * 8];
#pragma unroll
        for (int ni = 0; ni < 2; ni++) bfr[ni] = *(bf16x8*)&u.st.B[(wn * 32 + ni * 16 + c) * 40 + q * 8];
#pragma unroll
        for (int mi = 0; mi < 4; mi++)
#pragma unroll
            for (int ni = 0; ni < 2; ni++) acc[mi][ni] = MFMA16(af[mi], bfr[ni], acc[mi][ni]);
        __syncthreads();
    }
#pragma unroll
    for (int ni = 0; ni < 2; ni++)
#pragma unroll
        for (int mi = 0; mi < 4; mi++)
#pragma unroll
            for (int v = 0; v < 4; v++)
                u.E[(wm * 64 + mi * 16 + q * 4 + v) * 136 + wn * 32 + ni * 16 + c] =
                    (ushort_t)f2bs(acc[mi][ni][v]);
    __syncthreads();
    {
        int i = tid >> 2, p = tid & 3;
        int r = r0 + i, b = r >> 8, co = r & 255;
        short* dst = wc + (size_t)(b * 256 + co) * 1792 + n0 + p * 32;
        const ushort_t* src = &u.E[i * 136 + p * 32];
#pragma unroll
        for (int v = 0; v < 4; v++) *(uint4*)&dst[v * 8] = *(const uint4*)&src[v * 8];
    }
}

// ======================= per-sample conv + relu + maxpool =======================
// per b: [1024 x 1792] @ [1792 x 256]; A[s][kappa=k*256+ci] = x[b][s+k-3][ci]
__global__ __launch_bounds__(512) void k_conv(const short* __restrict__ xb,
        const short* __restrict__ wc, const float* __restrict__ cbias,
        float* __restrict__ out) {
    __shared__ union {
        struct { short A[128 * 72]; short B[256 * 72]; } st;
        ushort_t Y[128 * 256];
    } u;
    int bid = blockIdx.x;
    int bb = bid & 63, mt = bid >> 6;        // bid = mt*64+b : all mt of b on same XCD
    int s0 = mt * 126, p0 = mt * 42;
    int tid = threadIdx.x, lane = tid & 63, wid = tid >> 6;
    int wm = wid & 1, wn = wid >> 1;
    int q = lane >> 4, c = lane & 15;
    const short* xbb = xb + (size_t)bb * 262144;
    const short* wcb = wc + (size_t)bb * 458752;
    f32x4 acc[4][4];
#pragma unroll
    for (int mi = 0; mi < 4; mi++)
#pragma unroll
        for (int ni = 0; ni < 4; ni++) acc[mi][ni] = (f32x4){0.f, 0.f, 0.f, 0.f};
    for (int kc = 0; kc < 28; kc++) {
        int k = kc >> 2, c0 = (kc & 3) * 64;
        {   // A stage 128 x 64 (shifted x rows, zero-padded)
            int i = tid >> 2, p = tid & 3;
            int rs = s0 + i + k - 3;
            uint4 v0 = {0, 0, 0, 0}, v1 = {0, 0, 0, 0};
            if (rs >= 0 && rs < 1024) {
                const uint4* s = (const uint4*)&xbb[rs * 256 + c0 + p * 16];
                v0 = s[0]; v1 = s[1];
            }
            uint4* d = (uint4*)&u.st.A[i * 72 + p * 16];
            d[0] = v0; d[1] = v1;
        }
        {   // B stage 256co x 64kappa from WconvT[b][co][kappa]
            int co = tid >> 1, p = tid & 1;
            const uint4* s = (const uint4*)&wcb[co * 1792 + kc * 64 + p * 32];
            uint4* d = (uint4*)&u.st.B[co * 72 + p * 32];
            d[0] = s[0]; d[1] = s[1]; d[2] = s[2]; d[3] = s[3];
        }
        __syncthreads();
        bf16x8 af[4][2], bfr[4][2];
#pragma unroll
        for (int mi = 0; mi < 4; mi++)
#pragma unroll
            for (int kt = 0; kt < 2; kt++)
                af[mi][kt] = *(bf16x8*)&u.st.A[(wm * 64 + mi * 16 + c) * 72 + kt * 32 + q * 8];
#pragma unroll
        for (int ni = 0; ni < 4; ni++)
#pragma unroll
            for (int kt = 0; kt < 2; kt++)
                bfr[ni][kt] = *(bf16x8*)&u.st.B[(wn * 64 + ni * 16 + c) * 72 + kt * 32 + q * 8];
#pragma unroll
        for (int kt = 0; kt < 2; kt++)
#pragma unroll
            for (int mi = 0; mi < 4; mi++)
#pragma unroll
                for (int ni = 0; ni < 4; ni++)
                    acc[mi][ni] = MFMA16(af[mi][kt], bfr[ni][kt], acc[mi][ni]);
        __syncthreads();
    }
    // epilogue: +bias, relu, stage f16 y-tile
#pragma unroll
    for (int ni = 0; ni < 4; ni++) {
        int cg = wn * 64 + ni * 16 + c;
        float bias = cbias[cg];
#pragma unroll
        for (int mi = 0; mi < 4; mi++)
#pragma unroll
            for (int v = 0; v < 4; v++) {
                int rl = wm * 64 + mi * 16 + q * 4 + v;
                float val = acc[mi][ni][v] + bias;
                u.Y[rl * 256 + cg] = f16b(fmaxf(val, 0.f));
            }
    }
    __syncthreads();
    // maxpool(3): 42 pools x 256 channels
    for (int it = 0; it < 21; it++) {
        int idx = it * 512 + tid;
        int pp = idx >> 8, co = idx & 255;
        int p = p0 + pp;
        if (p < 341) {
            float a0 = h2f(u.Y[(3 * pp) * 256 + co]);
            float a1 = h2f(u.Y[(3 * pp + 1) * 256 + co]);
            float a2 = h2f(u.Y[(3 * pp + 2) * 256 + co]);
            out[(size_t)(bb * 341 + p) * 256 + co] = fmaxf(fmaxf(a0, a1), a2);
        }
    }
}

// ======================= launcher =======================
extern "C" void kernel_launch(void* const* d_in, const int* in_sizes, int n_in,
                              void* d_out, int out_size, void* d_ws, size_t ws_size,
                              hipStream_t stream) {
    const float* x    = (const float*)d_in[0];
    const float* gkf  = (const float*)d_in[2];
    const float* grf  = (const float*)d_in[3];
    const float* gbf  = (const float*)d_in[4];
    const float* gkb  = (const float*)d_in[5];
    const float* grb  = (const float*)d_in[6];
    const float* gbb  = (const float*)d_in[7];
    const float* Wa   = (const float*)d_in[8];
    const float* Wb   = (const float*)d_in[9];
    const float* cbias= (const float*)d_in[10];
    float* out = (float*)d_out;
    char* ws = (char*)d_ws;

    short*    xb   = (short*)(ws);                      // 33,554,432 B
    ushort_t* xp   = (ushort_t*)(ws + 33554432);        // 201,326,592 B (f+b, f16)
    short*    wkt  = (short*)(ws + 234881024);          // 786,432 B
    ushort_t* wrt  = (ushort_t*)(ws + 235667456);       // 786,432 B (Wr^T f16, both dirs)
    short*    wbt  = (short*)(ws + 236453888);          // 917,504 B
    float*    cbuf = (float*)(ws + 237371392);          // 131,072 B
    short*    aout = (short*)(ws + 237502464);          // 8,388,608 B
    short*    wc   = (short*)(ws + 245891072);          // 58,720,256 B  (end ~304.6 MB)

    hipLaunchKernelGGL(k_prep_x,   dim3(16384), dim3(256), 0, stream, x, xb);
    hipLaunchKernelGGL(k_prep_wk,  dim3(1536),  dim3(256), 0, stream, gkf, gkb, wkt);
    hipLaunchKernelGGL(k_prep_wrt, dim3(1536),  dim3(256), 0, stream, grf, grb, wrt);
    hipLaunchKernelGGL(k_prep_wb,  dim3(1792),  dim3(256), 0, stream, Wb, wbt);
    hipLaunchKernelGGL(k_proj,     dim3(6144),  dim3(512), 0, stream, xb, wkt, gbf, gbb, xp);
    hipLaunchKernelGGL(k_gru,      dim3(8),     dim3(512), 0, stream, wrt, xp, gbf, gbb, cbuf);
    hipLaunchKernelGGL(k_hyper1,   dim3(512),   dim3(256), 0, stream, cbuf, Wa, aout);
    hipLaunchKernelGGL(k_hyper2,   dim3(1792),  dim3(512), 0, stream, aout, wbt, wc);
    hipLaunchKernelGGL(k_conv,     dim3(576),   dim3(512), 0, stream, xb, wc, cbias, out);
}